// Round 17
// baseline (186.685 us; speedup 1.0000x reference)
//
#include <hip/hip_runtime.h>
#include <math.h>

constexpr int NB = 8, NC = 64, NO = 64, NH = 64, NW = 64;

using f32x4 = __attribute__((ext_vector_type(4))) float;
using s16x8 = __attribute__((ext_vector_type(8))) short;
using u32x4 = __attribute__((ext_vector_type(4))) unsigned int;

// packed f32x2 -> bf16x2 (RNE), v_cvt_pk_bf16_f32 (no builtin on gfx950)
__device__ __forceinline__ unsigned int pk2(float lo, float hi) {
    unsigned int r;
    asm("v_cvt_pk_bf16_f32 %0, %1, %2" : "=v"(r) : "v"(lo), "v"(hi));
    return r;
}
__device__ __forceinline__ float bf2f(unsigned short s) {
    unsigned u = ((unsigned)s) << 16;
    return __builtin_bit_cast(float, u);
}

// Grid 256 = b(8) x hoct(8) x osub(4) -> exactly 1 block/CU. Block 512 thr = 8 waves.
// Block tile: 8 h-rows x 64 w x 16 o (obase = osub*16). Wave wv = hrow, 4 n-tiles of 16 w.
// [R14-verified structure] + this round's delta: PATCH READ DIRECTLY FROM Xs (10 h-rows
// with +-1 halo; patch channels == x channels; R16-verified mechanism) -> no Patch array,
// no patch staging, ONE barrier total (R14 had 3).
// k-OUTER / a-INNER with tsum; MFMA A = W (rows=o), B = x (cols=w).
// D: row(o)=q*4+reg, col(w)=c0 -> coalesced stores.
// LDS 154.3 KB (Xs 80K + Ws 72K + bias 2.3K), 1 blk/CU. launch_bounds(512,1);
// live regs ~110 -> no spill (R5/R7/R11/R15 class avoided: no loop-resident staging regs).
__global__ __launch_bounds__(512, 1)
void acda_kernel(const float* __restrict__ x, const float* __restrict__ w_gen,
                 const float* __restrict__ b_gen, const float* __restrict__ pos_enc,
                 float* __restrict__ out)
{
    __shared__ unsigned short Xs[640 * 64];   // 80 KB [loc = hs*64+w][c] bf16 swz, hs: hbase-1..hbase+8
    __shared__ unsigned short Ws[16 * 36 * 64]; // 72 KB [o_l][t][c] bf16, XOR-swizzled
    __shared__ float BiasL[36 * 16];          // 2.3 KB [t][o_l]

    const int tid  = threadIdx.x;
    const int lane = tid & 63;
    const int wv   = tid >> 6;           // 0..7 = hrow
    const int c0   = lane & 15, q = lane >> 4;
    const int hrow = wv;

    const int bx    = blockIdx.x;
    const int osub  = bx & 3;
    const int hoct  = (bx >> 2) & 7;
    const int b     = bx >> 5;
    const int hbase = hoct * 8;
    const int obase = osub * 16;
    const size_t xB = (size_t)b * NC * NH * NW;

    // ---- stage Ws: w_gen[(obase+o_l)*36 + t][c] f32 -> Ws[o_l][t][c] bf16 swz (4608 x 16B) ----
    for (int u = tid; u < 4608; u += 512) {
        const int o_l = u / 288;
        const int r   = u - o_l * 288;
        const int t   = r >> 3, cseg = r & 7;
        const float* src = w_gen + ((size_t)(obase + o_l) * 36 + t) * NC + cseg * 8;
        const float4 v0 = *reinterpret_cast<const float4*>(src);
        const float4 v1 = *reinterpret_cast<const float4*>(src + 4);
        u32x4 pk;
        pk[0] = pk2(v0.x, v0.y); pk[1] = pk2(v0.z, v0.w);
        pk[2] = pk2(v1.x, v1.y); pk[3] = pk2(v1.z, v1.w);
        const int byte = (o_l * 36 + t) * 128 + ((cseg * 16) ^ ((o_l & 7) << 4));
        *reinterpret_cast<u32x4*>(reinterpret_cast<char*>(Ws) + byte) = pk;
    }
    // ---- stage Xs (10 rows, halo +-1; zeros outside): x[b,c,hh,w] -> Xs[hs*64+w][c] swz ----
    {
        const int w = lane;
#pragma unroll
        for (int i = 0; i < 10; ++i) {
            const int pair = wv * 10 + i;        // 80 (hs, oct) pairs
            const int hs = pair >> 3, oct = pair & 7;
            const int hh = hbase - 1 + hs;
            u32x4 pkv = {0, 0, 0, 0};
            if (hh >= 0 && hh < NH) {
                const float* src = x + xB + (size_t)(oct * 8) * (NH * NW) + hh * NW + w;
#pragma unroll
                for (int j = 0; j < 4; ++j)
                    pkv[j] = pk2(src[(size_t)(2 * j) * (NH * NW)], src[(size_t)(2 * j + 1) * (NH * NW)]);
            }
            const int loc  = hs * 64 + w;
            const int byte = loc * 128 + ((oct * 16) ^ ((loc & 7) << 4));
            *reinterpret_cast<u32x4*>(reinterpret_cast<char*>(Xs) + byte) = pkv;
        }
    }
    // ---- stage bias: BiasL[t*16 + o_l] = b_gen[(obase+o_l)*36 + t] ----
    for (int i = tid; i < 576; i += 512) {
        const int t = i >> 4, o_l = i & 15;
        BiasL[i] = b_gen[(obase + o_l) * 36 + t];
    }
    __syncthreads();   // the only barrier

    // ---- x fragments: 4 n-tiles from GEMM row hs = hrow+1 ----
    s16x8 xf[4][2];
#pragma unroll
    for (int nt = 0; nt < 4; ++nt) {
        const int loc = (hrow + 1) * 64 + nt * 16 + c0;
#pragma unroll
        for (int kh2 = 0; kh2 < 2; ++kh2) {
            const int byte = loc * 128 + ((kh2 * 64 + q * 16) ^ ((loc & 7) << 4));
            xf[nt][kh2] = *reinterpret_cast<s16x8*>(reinterpret_cast<char*>(Xs) + byte);
        }
    }

    // ---- attention attv[a][nt] ----
    const float gy = -1.0f + (2.0f / 63.0f) * (float)(hbase + hrow);
    float attv[4][4];
#pragma unroll
    for (int a = 0; a < 4; ++a) {
        const float px = pos_enc[2 * a], py = pos_enc[2 * a + 1];
#pragma unroll
        for (int nt = 0; nt < 4; ++nt) {
            const float gx = -1.0f + (2.0f / 63.0f) * (float)(nt * 16 + c0);
            const float dx = gx - px, dy = gy - py;
            attv[a][nt] = __expf(-(dx * dx + dy * dy));
        }
    }

    const int wswz = (c0 & 7) << 4;
    const char* wrowp = reinterpret_cast<const char*>(Ws) + c0 * (36 * 128);
    // patch addressing: channel = obase + q*4 (+r in the 8B read), chunk = (obase+q*4)>>3
    const int pchunk = (osub * 2 + (q >> 1)) * 16;   // byte offset of 8-channel chunk
    const int psub = (q & 1) * 8;                    // 4-channel sub-offset within chunk

    float outacc[4][4] = {};

#pragma unroll
    for (int k = 0; k < 9; ++k) {
        float tsum[4][4] = {};
#pragma unroll
        for (int a = 0; a < 4; ++a) {
            const int t = a * 9 + k;
            const s16x8 wf0 = *reinterpret_cast<const s16x8*>(wrowp + t * 128 + ((q * 16) ^ wswz));
            const s16x8 wf1 = *reinterpret_cast<const s16x8*>(wrowp + t * 128 + ((64 + q * 16) ^ wswz));
            const f32x4 bb  = *reinterpret_cast<const f32x4*>(BiasL + t * 16 + q * 4);
#pragma unroll
            for (int nt = 0; nt < 4; ++nt) {
                f32x4 acc = bb;
                acc = __builtin_amdgcn_mfma_f32_16x16x32_bf16(wf0, xf[nt][0], acc, 0, 0, 0);
                acc = __builtin_amdgcn_mfma_f32_16x16x32_bf16(wf1, xf[nt][1], acc, 0, 0, 0);
                const float at = attv[a][nt];
#pragma unroll
                for (int r = 0; r < 4; ++r)
                    tsum[nt][r] = fmaf(at, fmaxf(acc[r], 0.f), tsum[nt][r]);
            }
        }
        // ---- patch read from Xs (hs = hrow+kh, ww = w + kw - 1, w-clamped) ----
        const int kh = k / 3, kw = k - 3 * kh;
#pragma unroll
        for (int nt = 0; nt < 4; ++nt) {
            const int ww = nt * 16 + c0 + kw - 1;
            const bool wok = (ww >= 0) && (ww < NW);
            const int lp = (hrow + kh) * 64 + (wok ? ww : 0);
            const int byte = lp * 128 + (pchunk ^ ((lp & 7) << 4)) + psub;
            const ushort4 pu = *reinterpret_cast<const ushort4*>(
                reinterpret_cast<const char*>(Xs) + byte);
            const float p0 = wok ? bf2f(pu.x) : 0.f;
            const float p1 = wok ? bf2f(pu.y) : 0.f;
            const float p2 = wok ? bf2f(pu.z) : 0.f;
            const float p3 = wok ? bf2f(pu.w) : 0.f;
            outacc[nt][0] = fmaf(tsum[nt][0], p0, outacc[nt][0]);
            outacc[nt][1] = fmaf(tsum[nt][1], p1, outacc[nt][1]);
            outacc[nt][2] = fmaf(tsum[nt][2], p2, outacc[nt][2]);
            outacc[nt][3] = fmaf(tsum[nt][3], p3, outacc[nt][3]);
        }
    }

    // ---- coalesced stores: 16 consecutive w per 16-lane group ----
    const int h = hbase + hrow;
#pragma unroll
    for (int nt = 0; nt < 4; ++nt) {
        const int wcol = nt * 16 + c0;
#pragma unroll
        for (int r = 0; r < 4; ++r) {
            const int o = obase + q * 4 + r;
            out[(((size_t)b * NO + o) * NH + h) * NW + wcol] = outacc[nt][r];
        }
    }
}

extern "C" void kernel_launch(void* const* d_in, const int* in_sizes, int n_in,
                              void* d_out, int out_size, void* d_ws, size_t ws_size,
                              hipStream_t stream) {
    const float* x       = (const float*)d_in[0];
    const float* w_gen   = (const float*)d_in[1];
    const float* b_gen   = (const float*)d_in[2];
    const float* pos_enc = (const float*)d_in[3];
    float* out = (float*)d_out;

    dim3 grid(NB * 8 * 4);   // 256 workgroups = 1 per CU
    dim3 block(512);
    hipLaunchKernelGGL(acda_kernel, grid, block, 0, stream,
                       x, w_gen, b_gen, pos_enc, out);
}

// Round 18
// 27.930 us; speedup vs baseline: 6.6841x; 6.6841x over previous
//
#include <hip/hip_runtime.h>
#include <math.h>

constexpr int NB = 8, NC = 64, NO = 64, NH = 64, NW = 64;

using f32x4 = __attribute__((ext_vector_type(4))) float;
using s16x8 = __attribute__((ext_vector_type(8))) short;
using u32x4 = __attribute__((ext_vector_type(4))) unsigned int;

// packed f32x2 -> bf16x2 (RNE), v_cvt_pk_bf16_f32 (no builtin on gfx950)
__device__ __forceinline__ unsigned int pk2(float lo, float hi) {
    unsigned int r;
    asm("v_cvt_pk_bf16_f32 %0, %1, %2" : "=v"(r) : "v"(lo), "v"(hi));
    return r;
}
__device__ __forceinline__ float bf2f(unsigned short s) {
    unsigned u = ((unsigned)s) << 16;
    return __builtin_bit_cast(float, u);
}

// Grid 256 = b(8) x hoct(8) x osub(4) -> exactly 1 block/CU. Block 512 thr = 8 waves.
// Block tile: 8 h-rows x 64 w x 16 o (obase = osub*16). Wave wv = hrow, 4 n-tiles of 16 w.
// [R14-verified loop] + patch read DIRECTLY from Xs (mapping correctness-verified in R17).
// Xs holds 10 h-rows (h-halo +-1) x 66 w-cols (w-halo, cols 0/65 zeroed) -> patch read has
// NO selects: lp = (hrow+kh)*66 + nt*16+c0+kw. No Patch array, ONE barrier total.
// SPILL DISCIPLINE (R17 lesson): interior-row staging (hs=1..8) is UNCONDITIONAL (R14's
// proven 8-iter pattern); only 2 halo iterations/thread carry conditional loads.
// MFMA A = W (rows=o), B = x (cols=w). D: row(o)=q*4+reg, col(w)=c0 -> coalesced stores.
// LDS 160.5 KB (Xs 84.5K + Ws 73.7K + bias 2.3K), 1 blk/CU.
__global__ __launch_bounds__(512, 1)
void acda_kernel(const float* __restrict__ x, const float* __restrict__ w_gen,
                 const float* __restrict__ b_gen, const float* __restrict__ pos_enc,
                 float* __restrict__ out)
{
    __shared__ unsigned short Xs[660 * 64];     // 84.5 KB [loc = hs*66 + ww+1][c] bf16 swz
    __shared__ unsigned short Ws[16 * 36 * 64]; // 73.7 KB [o_l][t][c] bf16, XOR-swizzled
    __shared__ float BiasL[36 * 16];            // 2.3 KB [t][o_l]

    const int tid  = threadIdx.x;
    const int lane = tid & 63;
    const int wv   = tid >> 6;           // 0..7 = hrow
    const int c0   = lane & 15, q = lane >> 4;
    const int hrow = wv;

    const int bx    = blockIdx.x;
    const int osub  = bx & 3;
    const int hoct  = (bx >> 2) & 7;
    const int b     = bx >> 5;
    const int hbase = hoct * 8;
    const int obase = osub * 16;
    const size_t xB = (size_t)b * NC * NH * NW;

    // ---- stage Ws: w_gen[(obase+o_l)*36 + t][c] f32 -> Ws[o_l][t][c] bf16 swz (4608 x 16B) ----
    for (int u = tid; u < 4608; u += 512) {
        const int o_l = u / 288;
        const int r   = u - o_l * 288;
        const int t   = r >> 3, cseg = r & 7;
        const float* src = w_gen + ((size_t)(obase + o_l) * 36 + t) * NC + cseg * 8;
        const float4 v0 = *reinterpret_cast<const float4*>(src);
        const float4 v1 = *reinterpret_cast<const float4*>(src + 4);
        u32x4 pk;
        pk[0] = pk2(v0.x, v0.y); pk[1] = pk2(v0.z, v0.w);
        pk[2] = pk2(v1.x, v1.y); pk[3] = pk2(v1.z, v1.w);
        const int byte = (o_l * 36 + t) * 128 + ((cseg * 16) ^ ((o_l & 7) << 4));
        *reinterpret_cast<u32x4*>(reinterpret_cast<char*>(Ws) + byte) = pk;
    }
    // ---- stage Xs interior rows hs=1..8 (hh = hbase..hbase+7, ALWAYS valid -> unconditional) ----
    {
        const int w = lane;
#pragma unroll
        for (int i = 0; i < 8; ++i) {
            const int pair = wv * 8 + i;         // 64 (hs-1, oct) pairs
            const int hs = 1 + (pair >> 3), oct = pair & 7;
            const int hh = hbase - 1 + hs;
            const float* src = x + xB + (size_t)(oct * 8) * (NH * NW) + hh * NW + w;
            u32x4 pkv;
#pragma unroll
            for (int j = 0; j < 4; ++j)
                pkv[j] = pk2(src[(size_t)(2 * j) * (NH * NW)], src[(size_t)(2 * j + 1) * (NH * NW)]);
            const int loc  = hs * 66 + w + 1;
            const int byte = loc * 128 + ((oct * 16) ^ ((loc & 7) << 4));
            *reinterpret_cast<u32x4*>(reinterpret_cast<char*>(Xs) + byte) = pkv;
        }
        // halo rows hs=0 (hh=hbase-1) and hs=9 (hh=hbase+8): 16 pairs, 2/wave, conditional
#pragma unroll
        for (int i = 0; i < 2; ++i) {
            const int u2 = wv * 2 + i;           // 0..15
            const int hs = (u2 >> 3) * 9, oct = u2 & 7;
            const int hh = hbase - 1 + hs;
            u32x4 pkv = {0, 0, 0, 0};
            if (hh >= 0 && hh < NH) {
                const float* src = x + xB + (size_t)(oct * 8) * (NH * NW) + hh * NW + w;
#pragma unroll
                for (int j = 0; j < 4; ++j)
                    pkv[j] = pk2(src[(size_t)(2 * j) * (NH * NW)], src[(size_t)(2 * j + 1) * (NH * NW)]);
            }
            const int loc  = hs * 66 + w + 1;
            const int byte = loc * 128 + ((oct * 16) ^ ((loc & 7) << 4));
            *reinterpret_cast<u32x4*>(reinterpret_cast<char*>(Xs) + byte) = pkv;
        }
    }
    // ---- zero w-halo columns (ww+1 = 0 and 65) for all 10 rows: 160 x 16B units ----
    if (tid < 160) {
        const int cseg = tid & 7, side = (tid >> 3) & 1, hs = tid >> 4;
        const int loc = hs * 66 + (side ? 65 : 0);
        const int byte = loc * 128 + ((cseg * 16) ^ ((loc & 7) << 4));
        const u32x4 z = {0, 0, 0, 0};
        *reinterpret_cast<u32x4*>(reinterpret_cast<char*>(Xs) + byte) = z;
    }
    // ---- stage bias: BiasL[t*16 + o_l] = b_gen[(obase+o_l)*36 + t] ----
    for (int i = tid; i < 576; i += 512) {
        const int t = i >> 4, o_l = i & 15;
        BiasL[i] = b_gen[(obase + o_l) * 36 + t];
    }
    __syncthreads();   // the only barrier

    // ---- x fragments: 4 n-tiles from GEMM row hs = hrow+1, col index w+1 ----
    s16x8 xf[4][2];
#pragma unroll
    for (int nt = 0; nt < 4; ++nt) {
        const int loc = (hrow + 1) * 66 + nt * 16 + c0 + 1;
#pragma unroll
        for (int kh2 = 0; kh2 < 2; ++kh2) {
            const int byte = loc * 128 + ((kh2 * 64 + q * 16) ^ ((loc & 7) << 4));
            xf[nt][kh2] = *reinterpret_cast<s16x8*>(reinterpret_cast<char*>(Xs) + byte);
        }
    }

    // ---- attention attv[a][nt] ----
    const float gy = -1.0f + (2.0f / 63.0f) * (float)(hbase + hrow);
    float attv[4][4];
#pragma unroll
    for (int a = 0; a < 4; ++a) {
        const float px = pos_enc[2 * a], py = pos_enc[2 * a + 1];
#pragma unroll
        for (int nt = 0; nt < 4; ++nt) {
            const float gx = -1.0f + (2.0f / 63.0f) * (float)(nt * 16 + c0);
            const float dx = gx - px, dy = gy - py;
            attv[a][nt] = __expf(-(dx * dx + dy * dy));
        }
    }

    const int wswz = (c0 & 7) << 4;
    const char* wrowp = reinterpret_cast<const char*>(Ws) + c0 * (36 * 128);
    // patch addressing: channels obase+q*4..+3 -> chunk (osub*2 + (q>>1)), sub (q&1)*8
    const int pchunk = (osub * 2 + (q >> 1)) * 16;
    const int psub = (q & 1) * 8;

    float outacc[4][4] = {};

#pragma unroll
    for (int k = 0; k < 9; ++k) {
        float tsum[4][4] = {};
#pragma unroll
        for (int a = 0; a < 4; ++a) {
            const int t = a * 9 + k;
            const s16x8 wf0 = *reinterpret_cast<const s16x8*>(wrowp + t * 128 + ((q * 16) ^ wswz));
            const s16x8 wf1 = *reinterpret_cast<const s16x8*>(wrowp + t * 128 + ((64 + q * 16) ^ wswz));
            const f32x4 bb  = *reinterpret_cast<const f32x4*>(BiasL + t * 16 + q * 4);
#pragma unroll
            for (int nt = 0; nt < 4; ++nt) {
                f32x4 acc = bb;
                acc = __builtin_amdgcn_mfma_f32_16x16x32_bf16(wf0, xf[nt][0], acc, 0, 0, 0);
                acc = __builtin_amdgcn_mfma_f32_16x16x32_bf16(wf1, xf[nt][1], acc, 0, 0, 0);
                const float at = attv[a][nt];
#pragma unroll
                for (int r = 0; r < 4; ++r)
                    tsum[nt][r] = fmaf(at, fmaxf(acc[r], 0.f), tsum[nt][r]);
            }
        }
        // ---- patch read from Xs: row hs = hrow+kh, col index nt*16+c0+kw (w-halo'd) ----
        const int kh = k / 3, kw = k - 3 * kh;
#pragma unroll
        for (int nt = 0; nt < 4; ++nt) {
            const int lp = (hrow + kh) * 66 + nt * 16 + c0 + kw;
            const int byte = lp * 128 + (pchunk ^ ((lp & 7) << 4)) + psub;
            const ushort4 pu = *reinterpret_cast<const ushort4*>(
                reinterpret_cast<const char*>(Xs) + byte);
            outacc[nt][0] = fmaf(tsum[nt][0], bf2f(pu.x), outacc[nt][0]);
            outacc[nt][1] = fmaf(tsum[nt][1], bf2f(pu.y), outacc[nt][1]);
            outacc[nt][2] = fmaf(tsum[nt][2], bf2f(pu.z), outacc[nt][2]);
            outacc[nt][3] = fmaf(tsum[nt][3], bf2f(pu.w), outacc[nt][3]);
        }
    }

    // ---- coalesced stores: 16 consecutive w per 16-lane group ----
    const int h = hbase + hrow;
#pragma unroll
    for (int nt = 0; nt < 4; ++nt) {
        const int wcol = nt * 16 + c0;
#pragma unroll
        for (int r = 0; r < 4; ++r) {
            const int o = obase + q * 4 + r;
            out[(((size_t)b * NO + o) * NH + h) * NW + wcol] = outacc[nt][r];
        }
    }
}

extern "C" void kernel_launch(void* const* d_in, const int* in_sizes, int n_in,
                              void* d_out, int out_size, void* d_ws, size_t ws_size,
                              hipStream_t stream) {
    const float* x       = (const float*)d_in[0];
    const float* w_gen   = (const float*)d_in[1];
    const float* b_gen   = (const float*)d_in[2];
    const float* pos_enc = (const float*)d_in[3];
    float* out = (float*)d_out;

    dim3 grid(NB * 8 * 4);   // 256 workgroups = 1 per CU
    dim3 block(512);
    hipLaunchKernelGGL(acda_kernel, grid, block, 0, stream,
                       x, w_gen, b_gen, pos_enc, out);
}

// Round 19
// 21.628 us; speedup vs baseline: 8.6316x; 1.2914x over previous
//
#include <hip/hip_runtime.h>
#include <math.h>

constexpr int NB = 8, NC = 64, NO = 64, NH = 64, NW = 64;

using f32x4 = __attribute__((ext_vector_type(4))) float;
using s16x8 = __attribute__((ext_vector_type(8))) short;
using u32x4 = __attribute__((ext_vector_type(4))) unsigned int;

// packed f32x2 -> bf16x2 (RNE), v_cvt_pk_bf16_f32 (no builtin on gfx950)
__device__ __forceinline__ unsigned int pk2(float lo, float hi) {
    unsigned int r;
    asm("v_cvt_pk_bf16_f32 %0, %1, %2" : "=v"(r) : "v"(lo), "v"(hi));
    return r;
}
__device__ __forceinline__ unsigned short f2bf(float f) {
    unsigned u = __builtin_bit_cast(unsigned, f);
    return (unsigned short)((u + 0x7fffu + ((u >> 16) & 1u)) >> 16);
}
__device__ __forceinline__ float bf2f(unsigned short s) {
    unsigned u = ((unsigned)s) << 16;
    return __builtin_bit_cast(float, u);
}

// [R14-verified kernel, 25.9 us] + THIS ROUND'S SINGLE DELTA: XCD-aware blockIdx swizzle.
// The 4 osub-siblings of each (b,hoct) read the SAME 164 KB x-slab; default dispatch
// round-robins consecutive blockIdx across the 8 XCDs, so siblings hit 4 different L2s and
// each refetches the slab (measured FETCH 65.8 MB vs ~17 ideal). Remap so siblings share
// bx%8 (same XCD): xcd = bx&7, idx = bx>>3, osub = idx&3, g = xcd + 8*(idx>>2).  Bijective.
// Grid 256 = 1 block/CU. Block 512 thr = 8 waves; wave wv = hrow, 4 n-tiles of 16 w.
// Block tile: 8 h-rows x 64 w x 16 o. k-OUTER / a-INNER with tsum.
// MFMA A = W (rows=o), B = x (cols=w). D: row(o)=q*4+reg, col(w)=c0 -> coalesced stores.
// LDS 138.3 KB (arena Xs 64KB -> xf regs -> Patch 26.4KB; Ws 72KB; bias 2.3KB), 1 blk/CU.
__global__ __launch_bounds__(512, 1)
void acda_kernel(const float* __restrict__ x, const float* __restrict__ w_gen,
                 const float* __restrict__ b_gen, const float* __restrict__ pos_enc,
                 float* __restrict__ out)
{
    __shared__ __align__(16) unsigned char arena[65536];  // Xs [512 loc][64c] bf16 swz -> Patch [10][66][20] bf16
    __shared__ unsigned short Ws[16 * 36 * 64];           // 72 KB [o_l][t][c] bf16, XOR-swizzled
    __shared__ float BiasL[36 * 16];                      // 2.3 KB [t][o_l]

    const int tid  = threadIdx.x;
    const int lane = tid & 63;
    const int wv   = tid >> 6;           // 0..7 = hrow
    const int c0   = lane & 15, q = lane >> 4;
    const int hrow = wv;

    // ---- XCD-aware remap (T1): siblings (same b,hoct; osub=0..3) share bx%8 ----
    const int bx0  = blockIdx.x;         // 0..255
    const int xcd  = bx0 & 7;
    const int idx  = bx0 >> 3;           // 0..31 within XCD
    const int osub = idx & 3;
    const int g    = xcd + 8 * (idx >> 2);   // 0..63 = (b,hoct) group
    const int b    = g >> 3;
    const int hoct = g & 7;
    const int hbase = hoct * 8;
    const int obase = osub * 16;
    const size_t xB = (size_t)b * NC * NH * NW;

    // ---- stage Ws: w_gen[(obase+o_l)*36 + t][c] f32 -> Ws[o_l][t][c] bf16 swz (4608 x 16B) ----
    for (int u = tid; u < 4608; u += 512) {
        const int o_l = u / 288;
        const int r   = u - o_l * 288;
        const int t   = r >> 3, cseg = r & 7;
        const float* src = w_gen + ((size_t)(obase + o_l) * 36 + t) * NC + cseg * 8;
        const float4 v0 = *reinterpret_cast<const float4*>(src);
        const float4 v1 = *reinterpret_cast<const float4*>(src + 4);
        u32x4 pk;
        pk[0] = pk2(v0.x, v0.y); pk[1] = pk2(v0.z, v0.w);
        pk[2] = pk2(v1.x, v1.y); pk[3] = pk2(v1.z, v1.w);
        const int byte = (o_l * 36 + t) * 128 + ((cseg * 16) ^ ((o_l & 7) << 4));
        *reinterpret_cast<u32x4*>(reinterpret_cast<char*>(Ws) + byte) = pk;
    }
    // ---- stage Xs into arena: x[b,c,hbase+hs,w] -> [loc = hs*64+w][c] bf16 swz ----
    {
        const int w = lane;
#pragma unroll
        for (int i = 0; i < 8; ++i) {
            const int pair = wv * 8 + i;          // 64 (hs, oct) pairs
            const int hs = pair >> 3, oct = pair & 7;
            const float* src = x + xB + (size_t)(oct * 8) * (NH * NW) + (hbase + hs) * NW + w;
            u32x4 pkv;
#pragma unroll
            for (int j = 0; j < 4; ++j)
                pkv[j] = pk2(src[(size_t)(2 * j) * (NH * NW)], src[(size_t)(2 * j + 1) * (NH * NW)]);
            const int loc  = hs * 64 + w;
            const int byte = loc * 128 + ((oct * 16) ^ ((loc & 7) << 4));
            *reinterpret_cast<u32x4*>(arena + byte) = pkv;
        }
    }
    // ---- stage bias: BiasL[t*16 + o_l] = b_gen[(obase+o_l)*36 + t] ----
    for (int i = tid; i < 576; i += 512) {
        const int t = i >> 4, o_l = i & 15;
        BiasL[i] = b_gen[(obase + o_l) * 36 + t];
    }
    __syncthreads();   // Xs ready

    // ---- x fragments: 4 n-tiles (full h-row per wave) ----
    s16x8 xf[4][2];
#pragma unroll
    for (int nt = 0; nt < 4; ++nt) {
        const int loc = hrow * 64 + nt * 16 + c0;
#pragma unroll
        for (int kh2 = 0; kh2 < 2; ++kh2) {
            const int byte = loc * 128 + ((kh2 * 64 + q * 16) ^ ((loc & 7) << 4));
            xf[nt][kh2] = *reinterpret_cast<s16x8*>(arena + byte);
        }
    }
    __syncthreads();   // all Xs reads done; arena becomes Patch

    // ---- stage Patch: x[b,obase+o_l,hbase-1+hhi,w] -> Patch[hhi][w+1][o_l] bf16 ----
    unsigned short* Patch = reinterpret_cast<unsigned short*>(arena);
    {
        const int o_l = tid >> 5, w2 = (tid & 31) * 2;
        const float* xo = x + xB + (size_t)(obase + o_l) * (NH * NW);
#pragma unroll
        for (int hhi = 0; hhi < 10; ++hhi) {
            const int hh = hbase - 1 + hhi;
            float2 v = {0.f, 0.f};
            if (hh >= 0 && hh < NH) v = *reinterpret_cast<const float2*>(xo + hh * NW + w2);
            Patch[(hhi * 66 + w2 + 1) * 20 + o_l] = f2bf(v.x);
            Patch[(hhi * 66 + w2 + 2) * 20 + o_l] = f2bf(v.y);
        }
    }
    if (tid < 320) {   // zero halo columns wwi = 0, 65
        const int hhi = tid >> 5, side = (tid >> 4) & 1, o_l = tid & 15;
        Patch[(hhi * 66 + (side ? 65 : 0)) * 20 + o_l] = 0;
    }
    __syncthreads();   // Ws, Patch, BiasL ready

    // ---- attention attv[a][nt] ----
    const float gy = -1.0f + (2.0f / 63.0f) * (float)(hbase + hrow);
    float attv[4][4];
#pragma unroll
    for (int a = 0; a < 4; ++a) {
        const float px = pos_enc[2 * a], py = pos_enc[2 * a + 1];
#pragma unroll
        for (int nt = 0; nt < 4; ++nt) {
            const float gx = -1.0f + (2.0f / 63.0f) * (float)(nt * 16 + c0);
            const float dx = gx - px, dy = gy - py;
            attv[a][nt] = __expf(-(dx * dx + dy * dy));
        }
    }

    const int wswz = (c0 & 7) << 4;
    const char* wrowp = reinterpret_cast<const char*>(Ws) + c0 * (36 * 128);

    float outacc[4][4] = {};

#pragma unroll
    for (int k = 0; k < 9; ++k) {
        float tsum[4][4] = {};
#pragma unroll
        for (int a = 0; a < 4; ++a) {
            const int t = a * 9 + k;
            const s16x8 wf0 = *reinterpret_cast<const s16x8*>(wrowp + t * 128 + ((q * 16) ^ wswz));
            const s16x8 wf1 = *reinterpret_cast<const s16x8*>(wrowp + t * 128 + ((64 + q * 16) ^ wswz));
            const f32x4 bb  = *reinterpret_cast<const f32x4*>(BiasL + t * 16 + q * 4);
#pragma unroll
            for (int nt = 0; nt < 4; ++nt) {
                f32x4 acc = bb;
                acc = __builtin_amdgcn_mfma_f32_16x16x32_bf16(wf0, xf[nt][0], acc, 0, 0, 0);
                acc = __builtin_amdgcn_mfma_f32_16x16x32_bf16(wf1, xf[nt][1], acc, 0, 0, 0);
                const float at = attv[a][nt];
#pragma unroll
                for (int r = 0; r < 4; ++r)
                    tsum[nt][r] = fmaf(at, fmaxf(acc[r], 0.f), tsum[nt][r]);
            }
        }
        const int kh = k / 3, kw = k - 3 * kh;
#pragma unroll
        for (int nt = 0; nt < 4; ++nt) {
            const ushort4 pu = *reinterpret_cast<const ushort4*>(
                reinterpret_cast<const char*>(Patch) +
                (((hrow + kh) * 66 + nt * 16 + c0 + kw) * 20 + q * 4) * 2);
            outacc[nt][0] = fmaf(tsum[nt][0], bf2f(pu.x), outacc[nt][0]);
            outacc[nt][1] = fmaf(tsum[nt][1], bf2f(pu.y), outacc[nt][1]);
            outacc[nt][2] = fmaf(tsum[nt][2], bf2f(pu.z), outacc[nt][2]);
            outacc[nt][3] = fmaf(tsum[nt][3], bf2f(pu.w), outacc[nt][3]);
        }
    }

    // ---- coalesced stores: 16 consecutive w per 16-lane group ----
    const int h = hbase + hrow;
#pragma unroll
    for (int nt = 0; nt < 4; ++nt) {
        const int wcol = nt * 16 + c0;
#pragma unroll
        for (int r = 0; r < 4; ++r) {
            const int o = obase + q * 4 + r;
            out[(((size_t)b * NO + o) * NH + h) * NW + wcol] = outacc[nt][r];
        }
    }
}

extern "C" void kernel_launch(void* const* d_in, const int* in_sizes, int n_in,
                              void* d_out, int out_size, void* d_ws, size_t ws_size,
                              hipStream_t stream) {
    const float* x       = (const float*)d_in[0];
    const float* w_gen   = (const float*)d_in[1];
    const float* b_gen   = (const float*)d_in[2];
    const float* pos_enc = (const float*)d_in[3];
    float* out = (float*)d_out;

    dim3 grid(NB * 8 * 4);   // 256 workgroups = 1 per CU
    dim3 block(512);
    hipLaunchKernelGGL(acda_kernel, grid, block, 0, stream,
                       x, w_gen, b_gen, pos_enc, out);
}